// Round 6
// baseline (347.892 us; speedup 1.0000x reference)
//
#include <hip/hip_runtime.h>
#include <math.h>

#define NCLS 100
#define NBINS 15
#define NSEG (NCLS * NBINS)
#define NTOT (2 * NSEG + NCLS)   // conf[1500] | acc[1500] | total[100] = 3100
#define PSTRIDE 3104             // 64B-aligned partial rows (3104*4 = 12416)
#define RPI 8                    // rows per tile (4 slots x 2 rows)
#define GMAIN 2048               // 8 blocks/CU, all-resident (32 waves/CU)
#define NWAVES (GMAIN * 4)       // 8192

// Native fp32 atomic add (ds_add_f32 / global_atomic_add_f32).
__device__ __forceinline__ void fadd(float* p, float v) { unsafeAtomicAdd(p, v); }

__device__ __forceinline__ float readlane_f(float x, int l) {
    return __builtin_bit_cast(float, __builtin_amdgcn_readlane(__builtin_bit_cast(int, x), l));
}

// DPP wave64 sum step (VALU pipe only).
template <int CTRL>
__device__ __forceinline__ float dpp_add(float x) {
    int y = __builtin_amdgcn_update_dpp(0, __builtin_bit_cast(int, x),
                                        CTRL, 0xf, 0xf, true);
    return x + __builtin_bit_cast(float, y);
}

// ---- macros: everything in named registers, zero helper calls, so nothing
// ---- can be demoted to scratch (round-2 post-mortem).
// ---- NOTE (round-4/5 post-mortem): NEVER __builtin_nontemporal_store for
// ---- contiguous flushes on gfx950 -> 4.4x HBM write amplification.

// Unconditional clamp-addressed loads: exactly 5 VMEM ops, no branches.
// cqc = min(4q, 96): inactive lanes re-read the row's last 16B (no
// next-row overfetch). flim clamp only triggers for OOB prefetch tiles.
#define LOAD_TILE(E0, E1, E2, E3, LAB, TB) do {                               \
    (LAB) = labels[min((TB) + lane, N - 1)];                                  \
    const int _f = ((TB) + h) * NCLS + cqc;                                   \
    (E0) = *(const float4*)(logits + min(_f,            flim));               \
    (E1) = *(const float4*)(logits + min(_f + 2 * NCLS, flim));               \
    (E2) = *(const float4*)(logits + min(_f + 4 * NCLS, flim));               \
    (E3) = *(const float4*)(logits + min(_f + 6 * NCLS, flim));               \
} while (0)

// exp then zero invalid lanes/rows (cndmask; clamped loads always read real
// finite logits so exp never overflows). Zeroed E guarantees tails never
// fire for inactive lanes (e=0 fails the threshold and cq>=100 != lab).
#define EXPMASK(E, SOUT, VM) do {                                             \
    float _ex = __expf((E).x), _ey = __expf((E).y);                           \
    float _ez = __expf((E).z), _ew = __expf((E).w);                           \
    (E).x = (VM) ? _ex : 0.f; (E).y = (VM) ? _ey : 0.f;                       \
    (E).z = (VM) ? _ez : 0.f; (E).w = (VM) ? _ew : 0.f;                       \
    SOUT = ((E).x + (E).y) + ((E).z + (E).w);                                 \
} while (0)

// Fast path: gate on e > S/15 (<=> p*15 > 1 <=> bin >= 1, +-1ulp boundary
// fuzz is harmless: a conf-add routed to the bin-0 cell is IGNORED by the
// finalizer, which reconstructs conf0 = total - sum_{b>=1}; a boundary p
// folded into conf0 instead of bin1 shifts one class by ~p/N ~ 2e-9).
// t accumulates via fused fmaf (1 instr). Slow path ~1% of elements.
#define CLS_TAIL(EV, J, INV, TH, LABV) do {                                   \
    t##J = fmaf((EV), (INV), t##J);                                           \
    const bool _ch = (EV) > (TH);                                             \
    const bool _lh = (cq + (J)) == (LABV);                                    \
    if (_ch || _lh) {                                                         \
        const float _p = (EV) * (INV);                                        \
        const int _b = min((int)ceilf(_p * 15.f) - 1, NBINS - 1);             \
        if (_ch) fadd(&s_conf[(cq + (J)) * NBINS + _b], _p);                  \
        if (_lh) fadd(&s_acc[(cq + (J)) * NBINS + max(_b, 0)], 1.f);          \
    }                                                                         \
} while (0)

#define SLOT_TAIL(E, K, SV, TB, LAB, FULLV, REND) do {                        \
    const float _te = readlane_f(SV, 31);                                     \
    const float _to = readlane_f(SV, 63);                                     \
    const float _S  = h ? _to : _te;                                          \
    const float _inv = __builtin_amdgcn_rcpf(fmaxf(_S, 1e-30f));              \
    const float _th  = _S * (1.0f / 15.0f);                                   \
    int _le = __builtin_amdgcn_readlane(LAB, 2 * (K));                        \
    int _lo = __builtin_amdgcn_readlane(LAB, 2 * (K) + 1);                    \
    if (!(FULLV)) {                                                           \
        if ((TB) + 2 * (K)     >= (REND)) _le = -1;                           \
        if ((TB) + 2 * (K) + 1 >= (REND)) _lo = -1;                           \
    }                                                                         \
    const int _lab = h ? _lo : _le;                                           \
    CLS_TAIL((E).x, 0, _inv, _th, _lab);                                      \
    CLS_TAIL((E).y, 1, _inv, _th, _lab);                                      \
    CLS_TAIL((E).z, 2, _inv, _th, _lab);                                      \
    CLS_TAIL((E).w, 3, _inv, _th, _lab);                                      \
} while (0)

// Slot k covers rows TB+2k (half h=0) and TB+2k+1 (half h=1).
// 32-lane DPP reduce: lane31 = even-row total, lane63 = odd-row total.
// Row-validity masks compare against REND (slab end), not N.
#define COMPUTE_TILE(E0, E1, E2, E3, LAB, TB, FULLV, REND) do {               \
    const bool _v0 = act && ((FULLV) || ((TB) + 0 + h) < (REND));             \
    const bool _v1 = act && ((FULLV) || ((TB) + 2 + h) < (REND));             \
    const bool _v2 = act && ((FULLV) || ((TB) + 4 + h) < (REND));             \
    const bool _v3 = act && ((FULLV) || ((TB) + 6 + h) < (REND));             \
    float _s0, _s1, _s2, _s3;                                                 \
    EXPMASK(E0, _s0, _v0); EXPMASK(E1, _s1, _v1);                             \
    EXPMASK(E2, _s2, _v2); EXPMASK(E3, _s3, _v3);                             \
    _s0 = dpp_add<0x111>(_s0); _s1 = dpp_add<0x111>(_s1);                     \
    _s2 = dpp_add<0x111>(_s2); _s3 = dpp_add<0x111>(_s3);                     \
    _s0 = dpp_add<0x112>(_s0); _s1 = dpp_add<0x112>(_s1);                     \
    _s2 = dpp_add<0x112>(_s2); _s3 = dpp_add<0x112>(_s3);                     \
    _s0 = dpp_add<0x114>(_s0); _s1 = dpp_add<0x114>(_s1);                     \
    _s2 = dpp_add<0x114>(_s2); _s3 = dpp_add<0x114>(_s3);                     \
    _s0 = dpp_add<0x118>(_s0); _s1 = dpp_add<0x118>(_s1);                     \
    _s2 = dpp_add<0x118>(_s2); _s3 = dpp_add<0x118>(_s3);                     \
    _s0 = dpp_add<0x142>(_s0); _s1 = dpp_add<0x142>(_s1);                     \
    _s2 = dpp_add<0x142>(_s2); _s3 = dpp_add<0x142>(_s3);                     \
    SLOT_TAIL(E0, 0, _s0, TB, LAB, FULLV, REND);                              \
    SLOT_TAIL(E1, 1, _s1, TB, LAB, FULLV, REND);                              \
    SLOT_TAIL(E2, 2, _s2, TB, LAB, FULLV, REND);                              \
    SLOT_TAIL(E3, 3, _s3, TB, LAB, FULLV, REND);                              \
} while (0)

// lb(256,8): cap 64; measured VGPR use is 32-40 at depth-2 (R4/R5), so no
// spill risk. CONTIGUOUS SLAB per wave: wave g owns rows [r0, rend) walked
// sequentially -> one sequential DRAM stream per wave (round-5 post-mortem:
// the 20-26MB sweep stride gave 8192 scattered 3.2KB streams, suspected
// DRAM row-miss congestion behind the shape-invariant ~2 TB/s ceiling).
__global__ __launch_bounds__(256, 8) void ece_main_kernel(
    const float* __restrict__ logits,
    const int* __restrict__ labels,
    float* __restrict__ g_hist,     // [NTOT] (fallback atomic path)
    float* __restrict__ parts,      // [GMAIN][PSTRIDE] or nullptr
    int N)
{
    __shared__ float s_conf[NSEG];
    __shared__ float s_acc[NSEG];
    __shared__ float s_total[NCLS];
    for (int i = threadIdx.x; i < NSEG; i += 256) { s_conf[i] = 0.f; s_acc[i] = 0.f; }
    if (threadIdx.x < NCLS) s_total[threadIdx.x] = 0.f;
    __syncthreads();

    const int lane  = threadIdx.x & 63;
    const int wave  = threadIdx.x >> 6;
    const int gwave = blockIdx.x * 4 + wave;
    const int q     = lane & 31;            // class quad within half-wave
    const int h     = lane >> 5;            // row of the pair
    const int cq    = 4 * q;                // true class id (>=100 for pads)
    const int cqc   = min(cq, NCLS - 4);    // load offset: stay inside the row
    const bool act  = (q < NCLS / 4);       // q 0..24 hold classes
    const int flim  = N * NCLS - 4;         // flat clamp for OOB prefetch tiles

    // Contiguous slab assignment: every wave gets per or per+1 rows.
    const int per  = N / NWAVES;            // 61
    const int rem  = N - per * NWAVES;      // 248
    const int r0   = gwave * per + min(gwave, rem);
    const int rend = r0 + per + (gwave < rem ? 1 : 0);

    float t0 = 0.f, t1 = 0.f, t2 = 0.f, t3 = 0.f;
    float4 A0, A1, A2, A3, B0, B1, B2, B3;
    int labA, labB;
    int base = r0;

    // Depth-2 ping-pong over the slab, 2x unrolled (statically named bufs).
    LOAD_TILE(A0, A1, A2, A3, labA, base);
    while (base + 2 * RPI <= rend) {
        LOAD_TILE(B0, B1, B2, B3, labB, base + RPI);
        __builtin_amdgcn_sched_barrier(0);
        COMPUTE_TILE(A0, A1, A2, A3, labA, base, true, rend);
        LOAD_TILE(A0, A1, A2, A3, labA, base + 2 * RPI);   // clamped: safe OOB
        __builtin_amdgcn_sched_barrier(0);
        COMPUTE_TILE(B0, B1, B2, B3, labB, base + RPI, true, rend);
        base += 2 * RPI;
    }
    // Epilogue: A holds tile(base); at most one more partial tile follows.
    if (base < rend)
        COMPUTE_TILE(A0, A1, A2, A3, labA, base, false, rend);
    if (base + RPI < rend) {
        LOAD_TILE(B0, B1, B2, B3, labB, base + RPI);
        COMPUTE_TILE(B0, B1, B2, B3, labB, base + RPI, false, rend);
    }

    // Both halves hold totals for the same classes; LDS atomics merge.
    if (act) {
        fadd(&s_total[cq + 0], t0);
        fadd(&s_total[cq + 1], t1);
        fadd(&s_total[cq + 2], t2);
        fadd(&s_total[cq + 3], t3);
    }
    __syncthreads();

    if (parts) {
        // Two-stage path: plain contiguous stores (NOT nontemporal).
        float* my = parts + (size_t)blockIdx.x * PSTRIDE;
        for (int i = threadIdx.x; i < NSEG; i += 256) {
            my[i] = s_conf[i];
            my[NSEG + i] = s_acc[i];
        }
        if (threadIdx.x < NCLS)
            my[2 * NSEG + threadIdx.x] = s_total[threadIdx.x];
    } else {
        // Fallback: global-atomic flush (g_hist pre-zeroed by host).
        for (int i = threadIdx.x; i < NSEG; i += 256) {
            float v = s_conf[i]; if (v != 0.f) fadd(&g_hist[i], v);
            float a = s_acc[i];  if (a != 0.f) fadd(&g_hist[NSEG + i], a);
        }
        if (threadIdx.x < NCLS) {
            float tt = s_total[threadIdx.x];
            if (tt != 0.f) fadd(&g_hist[2 * NSEG + threadIdx.x], tt);
        }
    }
}

// Stage 2: fold GMAIN partials into g_hist. One writer per cell (plain
// store) -> no atomics, no pre-zero needed. 1024 thr = 16 waves; wave w
// sums chunk w (GMAIN/16 partials); lanes = 64 consecutive cells (256B).
__global__ __launch_bounds__(1024) void ece_reduce_kernel(
    const float* __restrict__ parts, float* __restrict__ g_hist, int nparts)
{
    const int lane = threadIdx.x & 63;
    const int wave = threadIdx.x >> 6;          // 0..15
    const int cell = blockIdx.x * 64 + lane;
    const int per = nparts / 16;
    float s = 0.f;
    if (cell < NTOT) {
        const float* bp = parts + (size_t)wave * per * PSTRIDE + cell;
        #pragma unroll 8
        for (int p = 0; p < per; ++p)
            s += bp[(size_t)p * PSTRIDE];
    }
    __shared__ float red[16][64];
    red[wave][lane] = s;
    __syncthreads();
    if (wave == 0) {
        float v = 0.f;
        #pragma unroll
        for (int w = 0; w < 16; ++w) v += red[w][lane];
        if (cell < NTOT) g_hist[cell] = v;
    }
}

// Finalize: conf0 = total - sum_{b>=1} conf_b; per-class sce; mean.
__global__ __launch_bounds__(128) void ece_final_kernel(
    const float* __restrict__ g_hist,
    float* __restrict__ out,
    float invN)
{
    __shared__ float red[128];
    const int t = threadIdx.x;
    float s = 0.f;
    if (t < NCLS) {
        float conf0 = g_hist[2 * NSEG + t];
        float sum = 0.f;
        #pragma unroll
        for (int b = 1; b < NBINS; ++b) {
            float cb = g_hist[t * NBINS + b];
            float ab = g_hist[NSEG + t * NBINS + b];
            conf0 -= cb;
            sum += fabsf(cb - ab);
        }
        sum += fabsf(conf0 - g_hist[NSEG + t * NBINS + 0]);
        s = sum * invN;
        out[1 + t] = s;
    }
    red[t] = s;
    __syncthreads();
    #pragma unroll
    for (int off = 64; off > 0; off >>= 1) {
        if (t < off) red[t] += red[t + off];
        __syncthreads();
    }
    if (t == 0) out[0] = red[0] * (1.0f / (float)NCLS);
}

extern "C" void kernel_launch(void* const* d_in, const int* in_sizes, int n_in,
                              void* d_out, int out_size, void* d_ws, size_t ws_size,
                              hipStream_t stream)
{
    const float* logits = (const float*)d_in[0];
    const int*   labels = (const int*)d_in[1];
    const int N = in_sizes[1];
    float* out = (float*)d_out;

    float* g_hist = (float*)d_ws;                         // [NTOT]
    const size_t parts_off = ((size_t)NTOT * sizeof(float) + 255) & ~(size_t)255;
    const size_t need = parts_off + (size_t)GMAIN * PSTRIDE * sizeof(float);
    float* parts = (ws_size >= need) ? (float*)((char*)d_ws + parts_off) : nullptr;

    if (!parts)   // atomic fallback needs a zeroed g_hist; two-stage does not
        (void)hipMemsetAsync(d_ws, 0, (size_t)NTOT * sizeof(float), stream);

    ece_main_kernel<<<GMAIN, 256, 0, stream>>>(logits, labels, g_hist, parts, N);
    if (parts)
        ece_reduce_kernel<<<(NTOT + 63) / 64, 1024, 0, stream>>>(parts, g_hist, GMAIN);
    ece_final_kernel<<<1, 128, 0, stream>>>(g_hist, out, 1.0f / (float)N);
}

// Round 7
// 285.666 us; speedup vs baseline: 1.2178x; 1.2178x over previous
//
#include <hip/hip_runtime.h>
#include <math.h>

#define NCLS 100
#define NBINS 15
#define NSEG (NCLS * NBINS)
#define NTOT (2 * NSEG + NCLS)   // conf[1500] | acc[1500] | total[100] = 3100
#define PSTRIDE 3104             // 64B-aligned partial rows (3104*4 = 12416)
#define TROWS 16                 // rows per staged tile (16*400B = 6400B)
#define GMAIN 512                // 2 blocks/CU (LDS-bound), all-resident
#define NWAVES (GMAIN * 4)       // 2048
#define STR (NWAVES * TROWS)     // 32768 rows between a wave's tiles

#define AS1(p) ((const __attribute__((address_space(1))) void*)(p))
#define AS3(p) ((__attribute__((address_space(3))) void*)(p))

// Native fp32 atomic add (ds_add_f32 / global_atomic_add_f32).
__device__ __forceinline__ void fadd(float* p, float v) { unsafeAtomicAdd(p, v); }

__device__ __forceinline__ float readlane_f(float x, int l) {
    return __builtin_bit_cast(float, __builtin_amdgcn_readlane(__builtin_bit_cast(int, x), l));
}

// DPP wave64 sum step (VALU pipe only).
template <int CTRL>
__device__ __forceinline__ float dpp_add(float x) {
    int y = __builtin_amdgcn_update_dpp(0, __builtin_bit_cast(int, x),
                                        CTRL, 0xf, 0xf, true);
    return x + __builtin_bit_cast(float, y);
}

// ---- round-7 structure: global_load_lds staging (the m13/m97-shaped VMEM
// ---- path: linear 1KB per instruction, fire-and-forget, counted vmcnt).
// ---- Wave-private LDS double buffer; NO barriers in the main loop.
// ---- Identity byte mapping: LDS[X] = global[TB*400 + X] for X in [0,6400).

// STAGE = 1 label load (VGPR, issued FIRST so its wait never over-drains)
// + 6x global_load_lds dwordx4 (1KB each) + 1x dword (256B) = 8 VMEM ops.
#define STAGE(SP, TB, LAB) do {                                               \
    (LAB) = labels[min((TB) + lane, N - 1)];                                  \
    const int _g = (TB) * NCLS + lane * 4;                                    \
    __builtin_amdgcn_global_load_lds(AS1(logits + min(_g,        NC4)), AS3((SP)       ), 16, 0, 0); \
    __builtin_amdgcn_global_load_lds(AS1(logits + min(_g +  256, NC4)), AS3((SP) + 1024), 16, 0, 0); \
    __builtin_amdgcn_global_load_lds(AS1(logits + min(_g +  512, NC4)), AS3((SP) + 2048), 16, 0, 0); \
    __builtin_amdgcn_global_load_lds(AS1(logits + min(_g +  768, NC4)), AS3((SP) + 3072), 16, 0, 0); \
    __builtin_amdgcn_global_load_lds(AS1(logits + min(_g + 1024, NC4)), AS3((SP) + 4096), 16, 0, 0); \
    __builtin_amdgcn_global_load_lds(AS1(logits + min(_g + 1280, NC4)), AS3((SP) + 5120), 16, 0, 0); \
    const int _g1 = (TB) * NCLS + 1536 + lane;                                \
    __builtin_amdgcn_global_load_lds(AS1(logits + min(_g1, NC1)), AS3((SP) + 6144), 4, 0, 0); \
} while (0)

// exp then zero invalid lanes/rows. Zeroed E guarantees tails never fire
// for inactive lanes (e=0 fails the threshold; cq>=100 never matches lab).
#define EXPMASK(E, SOUT, VM) do {                                             \
    float _ex = __expf((E).x), _ey = __expf((E).y);                           \
    float _ez = __expf((E).z), _ew = __expf((E).w);                           \
    (E).x = (VM) ? _ex : 0.f; (E).y = (VM) ? _ey : 0.f;                       \
    (E).z = (VM) ? _ez : 0.f; (E).w = (VM) ? _ew : 0.f;                       \
    SOUT = ((E).x + (E).y) + ((E).z + (E).w);                                 \
} while (0)

// Fast path: gate on e > S/15 (<=> p*15 > 1 <=> bin >= 1; +-1ulp boundary
// fuzz harmless: bin-0 conf cells are ignored by the finalizer, which
// reconstructs conf0 = total - sum_{b>=1}). Slow path ~1-2% of elements.
#define CLS_TAIL(EV, J, INV, TH, LABV) do {                                   \
    t##J = fmaf((EV), (INV), t##J);                                           \
    const bool _ch = (EV) > (TH);                                             \
    const bool _lh = (cq + (J)) == (LABV);                                    \
    if (_ch || _lh) {                                                         \
        const float _p = (EV) * (INV);                                        \
        const int _b = min((int)ceilf(_p * 15.f) - 1, NBINS - 1);             \
        if (_ch) fadd(&s_conf[(cq + (J)) * NBINS + _b], _p);                  \
        if (_lh) fadd(&s_acc[(cq + (J)) * NBINS + max(_b, 0)], 1.f);          \
    }                                                                         \
} while (0)

// Slot J covers rows TB+2J (half h=0) and TB+2J+1 (half h=1).
#define SLOT_TAIL(E, J, SV, TB, LAB, FULLV) do {                              \
    const float _te = readlane_f(SV, 31);                                     \
    const float _to = readlane_f(SV, 63);                                     \
    const float _S  = h ? _to : _te;                                          \
    const float _inv = __builtin_amdgcn_rcpf(fmaxf(_S, 1e-30f));              \
    const float _th  = _S * (1.0f / 15.0f);                                   \
    int _le = __builtin_amdgcn_readlane(LAB, 2 * (J));                        \
    int _lo = __builtin_amdgcn_readlane(LAB, 2 * (J) + 1);                    \
    if (!(FULLV)) {                                                           \
        if ((TB) + 2 * (J)     >= N) _le = -1;                                \
        if ((TB) + 2 * (J) + 1 >= N) _lo = -1;                                \
    }                                                                         \
    const int _lab = h ? _lo : _le;                                           \
    CLS_TAIL((E).x, 0, _inv, _th, _lab);                                      \
    CLS_TAIL((E).y, 1, _inv, _th, _lab);                                      \
    CLS_TAIL((E).z, 2, _inv, _th, _lab);                                      \
    CLS_TAIL((E).w, 3, _inv, _th, _lab);                                      \
} while (0)

// 16-row tile from LDS: 8 ds_read_b128 up front, 8 interleaved DPP chains,
// 8 slot tails. Lane (q,h): classes 4q..4q+3 of rows TB+2j+h.
#define COMPUTE16(SP, TB, LAB, FULLV) do {                                    \
    float4 F0 = *(const float4*)((SP) + ((0 + h) * 400 + cb));                \
    float4 F1 = *(const float4*)((SP) + ((2 + h) * 400 + cb));                \
    float4 F2 = *(const float4*)((SP) + ((4 + h) * 400 + cb));                \
    float4 F3 = *(const float4*)((SP) + ((6 + h) * 400 + cb));                \
    float4 F4 = *(const float4*)((SP) + ((8 + h) * 400 + cb));                \
    float4 F5 = *(const float4*)((SP) + ((10 + h) * 400 + cb));               \
    float4 F6 = *(const float4*)((SP) + ((12 + h) * 400 + cb));               \
    float4 F7 = *(const float4*)((SP) + ((14 + h) * 400 + cb));               \
    const bool _w0 = act && ((FULLV) || ((TB) + 0 + h) < N);                  \
    const bool _w1 = act && ((FULLV) || ((TB) + 2 + h) < N);                  \
    const bool _w2 = act && ((FULLV) || ((TB) + 4 + h) < N);                  \
    const bool _w3 = act && ((FULLV) || ((TB) + 6 + h) < N);                  \
    const bool _w4 = act && ((FULLV) || ((TB) + 8 + h) < N);                  \
    const bool _w5 = act && ((FULLV) || ((TB) + 10 + h) < N);                 \
    const bool _w6 = act && ((FULLV) || ((TB) + 12 + h) < N);                 \
    const bool _w7 = act && ((FULLV) || ((TB) + 14 + h) < N);                 \
    float _s0, _s1, _s2, _s3, _s4, _s5, _s6, _s7;                             \
    EXPMASK(F0, _s0, _w0); EXPMASK(F1, _s1, _w1);                             \
    EXPMASK(F2, _s2, _w2); EXPMASK(F3, _s3, _w3);                             \
    EXPMASK(F4, _s4, _w4); EXPMASK(F5, _s5, _w5);                             \
    EXPMASK(F6, _s6, _w6); EXPMASK(F7, _s7, _w7);                             \
    _s0 = dpp_add<0x111>(_s0); _s1 = dpp_add<0x111>(_s1);                     \
    _s2 = dpp_add<0x111>(_s2); _s3 = dpp_add<0x111>(_s3);                     \
    _s4 = dpp_add<0x111>(_s4); _s5 = dpp_add<0x111>(_s5);                     \
    _s6 = dpp_add<0x111>(_s6); _s7 = dpp_add<0x111>(_s7);                     \
    _s0 = dpp_add<0x112>(_s0); _s1 = dpp_add<0x112>(_s1);                     \
    _s2 = dpp_add<0x112>(_s2); _s3 = dpp_add<0x112>(_s3);                     \
    _s4 = dpp_add<0x112>(_s4); _s5 = dpp_add<0x112>(_s5);                     \
    _s6 = dpp_add<0x112>(_s6); _s7 = dpp_add<0x112>(_s7);                     \
    _s0 = dpp_add<0x114>(_s0); _s1 = dpp_add<0x114>(_s1);                     \
    _s2 = dpp_add<0x114>(_s2); _s3 = dpp_add<0x114>(_s3);                     \
    _s4 = dpp_add<0x114>(_s4); _s5 = dpp_add<0x114>(_s5);                     \
    _s6 = dpp_add<0x114>(_s6); _s7 = dpp_add<0x114>(_s7);                     \
    _s0 = dpp_add<0x118>(_s0); _s1 = dpp_add<0x118>(_s1);                     \
    _s2 = dpp_add<0x118>(_s2); _s3 = dpp_add<0x118>(_s3);                     \
    _s4 = dpp_add<0x118>(_s4); _s5 = dpp_add<0x118>(_s5);                     \
    _s6 = dpp_add<0x118>(_s6); _s7 = dpp_add<0x118>(_s7);                     \
    _s0 = dpp_add<0x142>(_s0); _s1 = dpp_add<0x142>(_s1);                     \
    _s2 = dpp_add<0x142>(_s2); _s3 = dpp_add<0x142>(_s3);                     \
    _s4 = dpp_add<0x142>(_s4); _s5 = dpp_add<0x142>(_s5);                     \
    _s6 = dpp_add<0x142>(_s6); _s7 = dpp_add<0x142>(_s7);                     \
    SLOT_TAIL(F0, 0, _s0, TB, LAB, FULLV);                                    \
    SLOT_TAIL(F1, 1, _s1, TB, LAB, FULLV);                                    \
    SLOT_TAIL(F2, 2, _s2, TB, LAB, FULLV);                                    \
    SLOT_TAIL(F3, 3, _s3, TB, LAB, FULLV);                                    \
    SLOT_TAIL(F4, 4, _s4, TB, LAB, FULLV);                                    \
    SLOT_TAIL(F5, 5, _s5, TB, LAB, FULLV);                                    \
    SLOT_TAIL(F6, 6, _s6, TB, LAB, FULLV);                                    \
    SLOT_TAIL(F7, 7, _s7, TB, LAB, FULLV);                                    \
} while (0)

// lb(256,2): VGPR cap huge -> spill impossible (R2/R4/R6 post-mortems:
// tight caps spill; reported VGPR_Count is arch-only, cap/2 signature).
// Occupancy is LDS-bound anyway: 63.6KB/block -> 2 blocks/CU.
__global__ __launch_bounds__(256, 2) void ece_main_kernel(
    const float* __restrict__ logits,
    const int* __restrict__ labels,
    float* __restrict__ g_hist,     // [NTOT] (fallback atomic path)
    float* __restrict__ parts,      // [GMAIN][PSTRIDE] or nullptr
    int N)
{
    __shared__ float s_conf[NSEG];
    __shared__ float s_acc[NSEG];
    __shared__ float s_total[NCLS];
    __shared__ __align__(16) unsigned char s_stage[4][2][TROWS * NCLS * 4];
    for (int i = threadIdx.x; i < NSEG; i += 256) { s_conf[i] = 0.f; s_acc[i] = 0.f; }
    if (threadIdx.x < NCLS) s_total[threadIdx.x] = 0.f;
    __syncthreads();

    const int lane  = threadIdx.x & 63;
    const int wave  = threadIdx.x >> 6;
    const int gwave = blockIdx.x * 4 + wave;
    const int q     = lane & 31;            // class quad within half-wave
    const int h     = lane >> 5;            // row of the pair
    const int cq    = 4 * q;                // true class id (>=100 for pads)
    const int cb    = min(cq, NCLS - 4) * 4;// LDS byte offset (clamped in-row)
    const bool act  = (q < NCLS / 4);       // q 0..24 hold classes
    const int NC4   = N * NCLS - 4;         // clamps for OOB prefetch tiles
    const int NC1   = N * NCLS - 1;

    float t0 = 0.f, t1 = 0.f, t2 = 0.f, t3 = 0.f;
    unsigned char* SP0 = &s_stage[wave][0][0];
    unsigned char* SP1 = &s_stage[wave][1][0];
    int labA = 0, labB = 0;
    int base = gwave * TROWS;

    if (base < N) {
        // Wave-private depth-2 ring: no __syncthreads in the loop; the only
        // sync is counted vmcnt (8 VMEM per STAGE group). Rule 18: asm wait
        // is followed by sched_barrier(0); "memory" clobber pins the ds_reads
        // and the new STAGE's loads on the correct sides of the wait.
        STAGE(SP0, base, labA);
        int nxt = base + STR;
        bool useA = true;
        while (nxt < N) {
            if (useA) {
                STAGE(SP1, nxt, labB);
                asm volatile("s_waitcnt vmcnt(8)" ::: "memory");
                __builtin_amdgcn_sched_barrier(0);
                COMPUTE16(SP0, base, labA, (base + TROWS <= N));
            } else {
                STAGE(SP0, nxt, labA);
                asm volatile("s_waitcnt vmcnt(8)" ::: "memory");
                __builtin_amdgcn_sched_barrier(0);
                COMPUTE16(SP1, base, labB, (base + TROWS <= N));
            }
            useA = !useA;
            base = nxt;
            nxt += STR;
        }
        asm volatile("s_waitcnt vmcnt(0)" ::: "memory");
        __builtin_amdgcn_sched_barrier(0);
        if (useA) COMPUTE16(SP0, base, labA, (base + TROWS <= N));
        else      COMPUTE16(SP1, base, labB, (base + TROWS <= N));
    }

    // Both halves hold totals for the same classes; LDS atomics merge.
    if (act) {
        fadd(&s_total[cq + 0], t0);
        fadd(&s_total[cq + 1], t1);
        fadd(&s_total[cq + 2], t2);
        fadd(&s_total[cq + 3], t3);
    }
    __syncthreads();

    if (parts) {
        // Two-stage path: plain contiguous stores (NOT nontemporal).
        float* my = parts + (size_t)blockIdx.x * PSTRIDE;
        for (int i = threadIdx.x; i < NSEG; i += 256) {
            my[i] = s_conf[i];
            my[NSEG + i] = s_acc[i];
        }
        if (threadIdx.x < NCLS)
            my[2 * NSEG + threadIdx.x] = s_total[threadIdx.x];
    } else {
        // Fallback: global-atomic flush (g_hist pre-zeroed by host).
        for (int i = threadIdx.x; i < NSEG; i += 256) {
            float v = s_conf[i]; if (v != 0.f) fadd(&g_hist[i], v);
            float a = s_acc[i];  if (a != 0.f) fadd(&g_hist[NSEG + i], a);
        }
        if (threadIdx.x < NCLS) {
            float tt = s_total[threadIdx.x];
            if (tt != 0.f) fadd(&g_hist[2 * NSEG + threadIdx.x], tt);
        }
    }
}

// Stage 2: fold GMAIN partials into g_hist. One writer per cell (plain
// store) -> no atomics, no pre-zero needed. 1024 thr = 16 waves; wave w
// sums chunk w (GMAIN/16 partials); lanes = 64 consecutive cells (256B).
__global__ __launch_bounds__(1024) void ece_reduce_kernel(
    const float* __restrict__ parts, float* __restrict__ g_hist, int nparts)
{
    const int lane = threadIdx.x & 63;
    const int wave = threadIdx.x >> 6;          // 0..15
    const int cell = blockIdx.x * 64 + lane;
    const int per = nparts / 16;
    float s = 0.f;
    if (cell < NTOT) {
        const float* bp = parts + (size_t)wave * per * PSTRIDE + cell;
        #pragma unroll 8
        for (int p = 0; p < per; ++p)
            s += bp[(size_t)p * PSTRIDE];
    }
    __shared__ float red[16][64];
    red[wave][lane] = s;
    __syncthreads();
    if (wave == 0) {
        float v = 0.f;
        #pragma unroll
        for (int w = 0; w < 16; ++w) v += red[w][lane];
        if (cell < NTOT) g_hist[cell] = v;
    }
}

// Finalize: conf0 = total - sum_{b>=1} conf_b; per-class sce; mean.
__global__ __launch_bounds__(128) void ece_final_kernel(
    const float* __restrict__ g_hist,
    float* __restrict__ out,
    float invN)
{
    __shared__ float red[128];
    const int t = threadIdx.x;
    float s = 0.f;
    if (t < NCLS) {
        float conf0 = g_hist[2 * NSEG + t];
        float sum = 0.f;
        #pragma unroll
        for (int b = 1; b < NBINS; ++b) {
            float cb = g_hist[t * NBINS + b];
            float ab = g_hist[NSEG + t * NBINS + b];
            conf0 -= cb;
            sum += fabsf(cb - ab);
        }
        sum += fabsf(conf0 - g_hist[NSEG + t * NBINS + 0]);
        s = sum * invN;
        out[1 + t] = s;
    }
    red[t] = s;
    __syncthreads();
    #pragma unroll
    for (int off = 64; off > 0; off >>= 1) {
        if (t < off) red[t] += red[t + off];
        __syncthreads();
    }
    if (t == 0) out[0] = red[0] * (1.0f / (float)NCLS);
}

extern "C" void kernel_launch(void* const* d_in, const int* in_sizes, int n_in,
                              void* d_out, int out_size, void* d_ws, size_t ws_size,
                              hipStream_t stream)
{
    const float* logits = (const float*)d_in[0];
    const int*   labels = (const int*)d_in[1];
    const int N = in_sizes[1];
    float* out = (float*)d_out;

    float* g_hist = (float*)d_ws;                         // [NTOT]
    const size_t parts_off = ((size_t)NTOT * sizeof(float) + 255) & ~(size_t)255;
    const size_t need = parts_off + (size_t)GMAIN * PSTRIDE * sizeof(float);
    float* parts = (ws_size >= need) ? (float*)((char*)d_ws + parts_off) : nullptr;

    if (!parts)   // atomic fallback needs a zeroed g_hist; two-stage does not
        (void)hipMemsetAsync(d_ws, 0, (size_t)NTOT * sizeof(float), stream);

    ece_main_kernel<<<GMAIN, 256, 0, stream>>>(logits, labels, g_hist, parts, N);
    if (parts)
        ece_reduce_kernel<<<(NTOT + 63) / 64, 1024, 0, stream>>>(parts, g_hist, GMAIN);
    ece_final_kernel<<<1, 128, 0, stream>>>(g_hist, out, 1.0f / (float)N);
}